// Round 4
// baseline (1182.417 us; speedup 1.0000x reference)
//
#include <hip/hip_runtime.h>

#define T_STEPS 500
#define N_NEUR  256
#define N_IN    256
#define N_BATCH 128

// ---------------------------------------------------------------------------
// Kernel 1: XW = X @ W_in   (M=64000, K=256, N=256), fp32 vector-ALU GEMM.
// (unchanged — known-correct numerics; optimize next round)
// ---------------------------------------------------------------------------
__global__ __launch_bounds__(256) void xw_gemm_kernel(
    const float* __restrict__ A,   // [M,256]
    const float* __restrict__ W,   // [256,256]
    float* __restrict__ C)         // [M,256]
{
    __shared__ float As[16][129];
    __shared__ float Bs[16][68];
    const int tid = threadIdx.x;
    const int bm  = blockIdx.x;
    const int bn  = blockIdx.y;
    const int ty  = tid >> 4;
    const int tx  = tid & 15;
    const int arow  = tid >> 1;
    const int akoff = (tid & 1) * 8;
    const int brow  = tid >> 4;
    const int bcol  = (tid & 15) * 4;
    const float* Ab = A + (size_t)bm * 128 * 256;

    float acc[8][4];
#pragma unroll
    for (int i = 0; i < 8; ++i)
#pragma unroll
        for (int j = 0; j < 4; ++j) acc[i][j] = 0.f;

    for (int k0 = 0; k0 < 256; k0 += 16) {
        float4 av0 = *(const float4*)(Ab + (size_t)arow * 256 + k0 + akoff);
        float4 av1 = *(const float4*)(Ab + (size_t)arow * 256 + k0 + akoff + 4);
        float4 bv  = *(const float4*)(W + (size_t)(k0 + brow) * 256 + bn * 64 + bcol);
        __syncthreads();
        As[akoff + 0][arow] = av0.x; As[akoff + 1][arow] = av0.y;
        As[akoff + 2][arow] = av0.z; As[akoff + 3][arow] = av0.w;
        As[akoff + 4][arow] = av1.x; As[akoff + 5][arow] = av1.y;
        As[akoff + 6][arow] = av1.z; As[akoff + 7][arow] = av1.w;
        *(float4*)&Bs[brow][bcol] = bv;
        __syncthreads();
#pragma unroll
        for (int kk = 0; kk < 16; ++kk) {
            float a[8], b[4];
#pragma unroll
            for (int i = 0; i < 8; ++i) a[i] = As[kk][ty * 8 + i];
#pragma unroll
            for (int j = 0; j < 4; ++j) b[j] = Bs[kk][tx * 4 + j];
#pragma unroll
            for (int i = 0; i < 8; ++i)
#pragma unroll
                for (int j = 0; j < 4; ++j)
                    acc[i][j] += a[i] * b[j];
        }
    }
    const int crow = bm * 128 + ty * 8;
    const int ccol = bn * 64 + tx * 4;
#pragma unroll
    for (int i = 0; i < 8; ++i) {
        float4 v = make_float4(acc[i][0], acc[i][1], acc[i][2], acc[i][3]);
        *(float4*)(C + (size_t)(crow + i) * 256 + ccol) = v;
    }
}

// ---------------------------------------------------------------------------
// Kernel 1b: column-permuted, diag-zeroed w_rec + zero sentinel row 256.
//   wzP[m][4*l + s] = (m == l+64s) ? 0 : w_rec[m][l + 64s]
// so a float4 at (row m, 4*lane) holds wz[m][lane + 64*{0,1,2,3}].
// ---------------------------------------------------------------------------
__global__ void prep_wrecP_kernel(const float* __restrict__ w_rec,
                                  float* __restrict__ wzP)
{
    int i = blockIdx.x * 256 + threadIdx.x;   // 0 .. 257*256-1
    int m  = i >> 8;
    int cp = i & 255;
    int c  = (cp >> 2) + 64 * (cp & 3);
    float val = 0.f;
    if (m < 256 && m != c) val = w_rec[m * 256 + c];
    wzP[i] = val;
}

// ---------------------------------------------------------------------------
// Kernel 2 (v3): barrier-free scan. One WAVE (64 threads) per batch; lane
// owns neurons {lane, lane+64, lane+128, lane+192}. Spike masks = 4 ballots
// (wave-uniform SGPRs) -> scalar-register walks; gather = float4 loads from
// wzP, double-buffered 32-deep. Numerics bit-identical to the R3-passing
// kernel: per-presyn-segment partials, ascending row order, 0.0 sentinel
// pads, ((P0+P1)+P2)+P3 combine, identical dynamics expressions.
// ---------------------------------------------------------------------------
#define CHUNK_EXTRACT_LOAD(CH)                                               \
    {                                                                        \
        _Pragma("unroll")                                                    \
        for (int j = 0; j < 8; ++j) {                                        \
            int r0 = m0 ? (__builtin_ctzll(m0) + 0)   : 256;  m0 &= m0 - 1;  \
            int r1 = m1 ? (__builtin_ctzll(m1) + 64)  : 256;  m1 &= m1 - 1;  \
            int r2 = m2 ? (__builtin_ctzll(m2) + 128) : 256;  m2 &= m2 - 1;  \
            int r3 = m3 ? (__builtin_ctzll(m3) + 192) : 256;  m3 &= m3 - 1;  \
            CH##0[j] = *(const float4*)(wzP + r0 * 256 + lane4);             \
            CH##1[j] = *(const float4*)(wzP + r1 * 256 + lane4);             \
            CH##2[j] = *(const float4*)(wzP + r2 * 256 + lane4);             \
            CH##3[j] = *(const float4*)(wzP + r3 * 256 + lane4);             \
        }                                                                    \
    }

#define CHUNK_ACCUM(CH)                                                      \
    {                                                                        \
        _Pragma("unroll")                                                    \
        for (int j = 0; j < 8; ++j) {                                        \
            P0.x += CH##0[j].x; P0.y += CH##0[j].y;                          \
            P0.z += CH##0[j].z; P0.w += CH##0[j].w;                          \
        }                                                                    \
        _Pragma("unroll")                                                    \
        for (int j = 0; j < 8; ++j) {                                        \
            P1.x += CH##1[j].x; P1.y += CH##1[j].y;                          \
            P1.z += CH##1[j].z; P1.w += CH##1[j].w;                          \
        }                                                                    \
        _Pragma("unroll")                                                    \
        for (int j = 0; j < 8; ++j) {                                        \
            P2.x += CH##2[j].x; P2.y += CH##2[j].y;                          \
            P2.z += CH##2[j].z; P2.w += CH##2[j].w;                          \
        }                                                                    \
        _Pragma("unroll")                                                    \
        for (int j = 0; j < 8; ++j) {                                        \
            P3.x += CH##3[j].x; P3.y += CH##3[j].y;                          \
            P3.z += CH##3[j].z; P3.w += CH##3[j].w;                          \
        }                                                                    \
    }

__global__ __launch_bounds__(64, 1) void lsnn_scan3_kernel(
    const float* __restrict__ xw,    // [B,T,N]
    const float* __restrict__ wzP,   // [257,256] permuted, diag-zeroed
    const float* __restrict__ z0, const float* __restrict__ v0,
    const float* __restrict__ a0, const float* __restrict__ lsd0,
    float* __restrict__ out)         // [4,T,B,N]
{
    const int b     = blockIdx.x;
    const int lane  = threadIdx.x;
    const int lane4 = lane * 4;

    const float dv   = (float)0.9512294245007140018;  // exp(-1/20) fp32
    const float omdv = 1.0f - dv;

    float z[4], v[4], a[4], lsd[4];
#pragma unroll
    for (int s = 0; s < 4; ++s) {
        int idx = b * N_NEUR + lane + 64 * s;
        z[s]   = z0[idx];
        v[s]   = v0[idx];
        a[s]   = a0[idx];
        lsd[s] = lsd0[idx];
    }

    unsigned long long M0 = __ballot(z[0] != 0.f);
    unsigned long long M1 = __ballot(z[1] != 0.f);
    unsigned long long M2 = __ballot(z[2] != 0.f);
    unsigned long long M3 = __ballot(z[3] != 0.f);

    const float* xwb = xw + (size_t)b * T_STEPS * N_NEUR + lane;
    const size_t PL  = (size_t)T_STEPS * N_BATCH * N_NEUR;

    float xn[4];
#pragma unroll
    for (int s = 0; s < 4; ++s) xn[s] = xwb[64 * s];

    for (int t = 0; t < T_STEPS; ++t) {
        float xc[4];
#pragma unroll
        for (int s = 0; s < 4; ++s) xc[s] = xn[s];
        {
            int tn = (t + 1 < T_STEPS) ? t + 1 : t;
#pragma unroll
            for (int s = 0; s < 4; ++s)
                xn[s] = xwb[(size_t)tn * N_NEUR + 64 * s];
        }

        // ---- sparse gather, double-buffered ------------------------------
        unsigned long long m0 = M0, m1 = M1, m2 = M2, m3 = M3;
        float4 P0 = make_float4(0.f, 0.f, 0.f, 0.f);
        float4 P1 = make_float4(0.f, 0.f, 0.f, 0.f);
        float4 P2 = make_float4(0.f, 0.f, 0.f, 0.f);
        float4 P3 = make_float4(0.f, 0.f, 0.f, 0.f);

        if (m0 | m1 | m2 | m3) {
            float4 A0[8], A1[8], A2[8], A3[8];
            float4 B0[8], B1[8], B2[8], B3[8];
            CHUNK_EXTRACT_LOAD(A)
            for (;;) {
                if (!(m0 | m1 | m2 | m3)) { CHUNK_ACCUM(A) break; }
                CHUNK_EXTRACT_LOAD(B)
                CHUNK_ACCUM(A)
                if (!(m0 | m1 | m2 | m3)) { CHUNK_ACCUM(B) break; }
                CHUNK_EXTRACT_LOAD(A)
                CHUNK_ACCUM(B)
            }
        }

        // ---- dynamics + stores per owned neuron --------------------------
        size_t o = (size_t)t * (N_BATCH * N_NEUR) + (size_t)b * N_NEUR + lane;
#pragma unroll
        for (int s = 0; s < 4; ++s) {
            float ir = (s == 0) ? (((P0.x + P1.x) + P2.x) + P3.x)
                     : (s == 1) ? (((P0.y + P1.y) + P2.y) + P3.y)
                     : (s == 2) ? (((P0.z + P1.z) + P2.z) + P3.z)
                                : (((P0.w + P1.w) + P2.w) + P3.w);
            float i_in  = xc[s] + ir;                 // INTERNAL_CURRENT == 0
            float new_a = dv * a[s] + omdv * z[s];
            float thr   = 0.03f + new_a * 1.8f;
            float new_v = dv * v[s] + omdv * i_in - thr * z[s];
            float v_sc  = (new_v - thr) / thr;
            float zs    = (v_sc > 0.f) ? 1.f : 0.f;
            zs          = (lsd[s] >= 2.0f) ? zs : 0.f;
            float new_lsd = (lsd[s] + 1.f) * (1.f - zs);

            __builtin_nontemporal_store(zs,    out + o + 64 * s);
            __builtin_nontemporal_store(new_v, out + o + PL + 64 * s);
            __builtin_nontemporal_store(thr,   out + o + 2 * PL + 64 * s);
            __builtin_nontemporal_store(v_sc,  out + o + 3 * PL + 64 * s);

            v[s] = new_v; a[s] = new_a; lsd[s] = new_lsd; z[s] = zs;
        }

        M0 = __ballot(z[0] != 0.f);
        M1 = __ballot(z[1] != 0.f);
        M2 = __ballot(z[2] != 0.f);
        M3 = __ballot(z[3] != 0.f);
    }
}

// ---------------------------------------------------------------------------
// Fallback scan (R1 version) — used only if ws_size is too small.
// ---------------------------------------------------------------------------
template <bool USE_XW>
__global__ __launch_bounds__(256) void lsnn_scan_kernel(
    const float* __restrict__ xin,
    const float* __restrict__ w_in,
    const float* __restrict__ w_rec,
    const float* __restrict__ z0, const float* __restrict__ v0,
    const float* __restrict__ a0, const float* __restrict__ lsd0,
    float* __restrict__ out)
{
    const int b    = blockIdx.x;
    const int n    = threadIdx.x;
    const int lane = n & 63;
    const int wid  = n >> 6;

    __shared__ int   cnt4[4];
    __shared__ int   act[256];
    __shared__ float xsh[256];

    const float dv   = (float)0.9512294245007140018;
    const float omdv = 1.0f - dv;

    const int base_bn = b * N_NEUR + n;
    float z   = z0[base_bn];
    float v   = v0[base_bn];
    float a   = a0[base_bn];
    float lsd = lsd0[base_bn];

    act[n] = 0;
    {
        unsigned long long wm = __ballot(z != 0.f);
        if (lane == 0) cnt4[wid] = __popcll(wm);
        if (z != 0.f) {
            int pos = __popcll(wm & ((1ull << lane) - 1ull));
            act[wid * 64 + pos] = n;
        }
        if (!USE_XW) xsh[n] = xin[((size_t)b * T_STEPS) * N_IN + n];
    }
    __syncthreads();

    float x_next = USE_XW ? xin[((size_t)b * T_STEPS) * N_NEUR + n] : 0.f;

    for (int t = 0; t < T_STEPS; ++t) {
        float x_cur = x_next;
        if (USE_XW) {
            int tn = (t + 1 < T_STEPS) ? t + 1 : t;
            x_next = xin[((size_t)b * T_STEPS + tn) * N_NEUR + n];
        }
        const int cs0 = cnt4[0], cs1 = cnt4[1], cs2 = cnt4[2], cs3 = cnt4[3];
        int mx = max(max(cs0, cs1), max(cs2, cs3));
        float r0 = 0.f, r1 = 0.f, r2 = 0.f, r3 = 0.f;
        for (int i0 = 0; i0 < mx; i0 += 8) {
            float wv[4][8];
            bool  ok[4][8];
#pragma unroll
            for (int s = 0; s < 4; ++s) {
                const int cs = (s == 0) ? cs0 : (s == 1) ? cs1 : (s == 2) ? cs2 : cs3;
#pragma unroll
                for (int j = 0; j < 8; ++j) {
                    int ii = i0 + j;
                    int m  = act[s * 64 + (ii < cs ? ii : 0)] & 255;
                    wv[s][j] = w_rec[m * N_NEUR + n];
                    ok[s][j] = (ii < cs) && (m != n);
                }
            }
#pragma unroll
            for (int j = 0; j < 8; ++j) r0 += ok[0][j] ? wv[0][j] : 0.f;
#pragma unroll
            for (int j = 0; j < 8; ++j) r1 += ok[1][j] ? wv[1][j] : 0.f;
#pragma unroll
            for (int j = 0; j < 8; ++j) r2 += ok[2][j] ? wv[2][j] : 0.f;
#pragma unroll
            for (int j = 0; j < 8; ++j) r3 += ok[3][j] ? wv[3][j] : 0.f;
        }
        float i_rec = ((r0 + r1) + r2) + r3;

        float xdot;
        if (USE_XW) {
            xdot = x_cur;
        } else {
            float s = 0.f;
#pragma unroll 8
            for (int m = 0; m < N_IN; ++m) s += xsh[m] * w_in[m * N_NEUR + n];
            xdot = s;
        }
        float i_in = xdot + i_rec;

        float new_a = dv * a + omdv * z;
        float thr   = 0.03f + new_a * 1.8f;
        float new_v = dv * v + omdv * i_in - thr * z;
        float v_sc  = (new_v - thr) / thr;
        float zs    = (v_sc > 0.f) ? 1.f : 0.f;
        zs          = (lsd >= 2.0f) ? zs : 0.f;
        float new_lsd = (lsd + 1.f) * (1.f - zs);

        const size_t PL = (size_t)T_STEPS * N_BATCH * N_NEUR;
        size_t o = (size_t)t * (N_BATCH * N_NEUR) + (size_t)b * N_NEUR + n;
        out[o]          = zs;
        out[o + PL]     = new_v;
        out[o + 2 * PL] = thr;
        out[o + 3 * PL] = v_sc;

        v = new_v; a = new_a; lsd = new_lsd; z = zs;

        __syncthreads();
        unsigned long long wm = __ballot(zs != 0.f);
        if (lane == 0) cnt4[wid] = __popcll(wm);
        if (zs != 0.f) {
            int pos = __popcll(wm & ((1ull << lane) - 1ull));
            act[wid * 64 + pos] = n;
        }
        if (!USE_XW && (t + 1 < T_STEPS))
            xsh[n] = xin[((size_t)b * T_STEPS + t + 1) * N_IN + n];
        __syncthreads();
    }
}

// ---------------------------------------------------------------------------
extern "C" void kernel_launch(void* const* d_in, const int* in_sizes, int n_in,
                              void* d_out, int out_size, void* d_ws, size_t ws_size,
                              hipStream_t stream) {
    const float* x     = (const float*)d_in[0];
    const float* w_in  = (const float*)d_in[1];
    const float* w_rec = (const float*)d_in[2];
    const float* z0    = (const float*)d_in[3];
    const float* v0    = (const float*)d_in[4];
    const float* a0    = (const float*)d_in[5];
    const float* lsd0  = (const float*)d_in[6];
    float* out = (float*)d_out;

    const size_t xw_bytes = (size_t)N_BATCH * T_STEPS * N_NEUR * sizeof(float);
    const size_t wz_bytes = (size_t)257 * 256 * sizeof(float);

    if (ws_size >= xw_bytes + wz_bytes) {
        float* xw  = (float*)d_ws;
        float* wzP = (float*)((char*)d_ws + xw_bytes);
        prep_wrecP_kernel<<<257, 256, 0, stream>>>(w_rec, wzP);
        dim3 grid(500, 4, 1);
        xw_gemm_kernel<<<grid, 256, 0, stream>>>(x, w_in, xw);
        lsnn_scan3_kernel<<<N_BATCH, 64, 0, stream>>>(
            xw, wzP, z0, v0, a0, lsd0, out);
    } else if (ws_size >= xw_bytes) {
        float* xw = (float*)d_ws;
        dim3 grid(500, 4, 1);
        xw_gemm_kernel<<<grid, 256, 0, stream>>>(x, w_in, xw);
        lsnn_scan_kernel<true><<<N_BATCH, 256, 0, stream>>>(
            xw, nullptr, w_rec, z0, v0, a0, lsd0, out);
    } else {
        lsnn_scan_kernel<false><<<N_BATCH, 256, 0, stream>>>(
            x, w_in, w_rec, z0, v0, a0, lsd0, out);
    }
}